// Round 3
// baseline (4300.766 us; speedup 1.0000x reference)
//
#include <hip/hip_runtime.h>
#include <stdint.h>

#define T_TOKENS 16384
#define D_IN     1024
#define D_HID    2048
#define D_OUT    1024
#define N_EXP    8
#define MAX_ROWS 34816   // 136 * 256 (2*T + 8*255 pad, 256-block granularity)

typedef short  short8  __attribute__((ext_vector_type(8)));
typedef float  f32x4   __attribute__((ext_vector_type(4)));

#define LDS_AS __attribute__((address_space(3)))
#define GLB_AS __attribute__((address_space(1)))

__device__ __forceinline__ unsigned short f2bf_rne(float f) {
  uint32_t u = __builtin_bit_cast(uint32_t, f);
  u += 0x7fff + ((u >> 16) & 1);
  return (unsigned short)(u >> 16);
}
__device__ __forceinline__ float bf2f(unsigned short h) {
  uint32_t u = ((uint32_t)h) << 16;
  return __builtin_bit_cast(float, u);
}
// truncation split: hi = trunc-bf16(a), lo = RNE-bf16(a - hi)  (matches r2 numerics)
__device__ __forceinline__ void split2(float a, float b, uint32_t& hw, uint32_t& lw) {
  uint32_t ua = __builtin_bit_cast(uint32_t, a);
  uint32_t ub = __builtin_bit_cast(uint32_t, b);
  hw = (ua >> 16) | (ub & 0xffff0000u);
  float ra = a - __builtin_bit_cast(float, ua & 0xffff0000u);
  float rb = b - __builtin_bit_cast(float, ub & 0xffff0000u);
  uint32_t ura = __builtin_bit_cast(uint32_t, ra);
  uint32_t urb = __builtin_bit_cast(uint32_t, rb);
  lw = (f2bf_rne(__builtin_bit_cast(float, ura & 0xffffffffu)) ) | ((uint32_t)f2bf_rne(rb) << 16);
  (void)urb;
}

// ---------------------------------------------------------------------------
// Gate: fp32 logits -> softmax -> top2 -> renorm weights; expert histogram.
// Also: split x into bf16 hi/lo planes, and write out = x (residual init).
__global__ __launch_bounds__(256) void k_gate(
    const float* __restrict__ x, const float* __restrict__ gw,
    unsigned short* __restrict__ xs_hi, unsigned short* __restrict__ xs_lo,
    float* __restrict__ outp, int4* __restrict__ tokexp, int* __restrict__ counts)
{
  __shared__ float gwT[8][1024];
  __shared__ int cnt[8];
  int tid = threadIdx.x;
  if (tid < 8) cnt[tid] = 0;
  for (int i = tid; i < D_IN * N_EXP; i += 256) gwT[i & 7][i >> 3] = gw[i];
  __syncthreads();
  int wave = tid >> 6, lane = tid & 63;
  for (int tt = 0; tt < 16; ++tt) {
    int t = blockIdx.x * 64 + wave * 16 + tt;
    const float4* x4 = (const float4*)(x + (size_t)t * D_IN);
    float4 v[4];
#pragma unroll
    for (int j = 0; j < 4; ++j) v[j] = x4[j * 64 + lane];
    // residual init + split-store x planes
#pragma unroll
    for (int j = 0; j < 4; ++j) {
      size_t off = (size_t)t * D_IN + (size_t)(j * 64 + lane) * 4;
      *(float4*)(outp + off) = v[j];
      ushort4 h4, l4;
      float* vp = (float*)&v[j];
      unsigned short* hp = (unsigned short*)&h4;
      unsigned short* lp = (unsigned short*)&l4;
#pragma unroll
      for (int c = 0; c < 4; ++c) {
        uint32_t u = __builtin_bit_cast(uint32_t, vp[c]);
        unsigned short hh = (unsigned short)(u >> 16);             // trunc hi
        float res = vp[c] - __builtin_bit_cast(float, u & 0xffff0000u);
        hp[c] = hh; lp[c] = f2bf_rne(res);
      }
      *(ushort4*)(xs_hi + off) = h4;
      *(ushort4*)(xs_lo + off) = l4;
    }
    float a[8];
#pragma unroll
    for (int e = 0; e < 8; ++e) a[e] = 0.f;
#pragma unroll
    for (int e = 0; e < 8; ++e) {
#pragma unroll
      for (int j = 0; j < 4; ++j) {
        float4 g4 = ((const float4*)gwT[e])[j * 64 + lane];
        float* vp = (float*)&v[j];
        a[e] += vp[0] * g4.x + vp[1] * g4.y + vp[2] * g4.z + vp[3] * g4.w;
      }
    }
#pragma unroll
    for (int e = 0; e < 8; ++e) {
#pragma unroll
      for (int s = 32; s >= 1; s >>= 1) a[e] += __shfl_xor(a[e], s, 64);
    }
    if (lane == 0) {
      float m = a[0];
#pragma unroll
      for (int e = 1; e < 8; ++e) m = fmaxf(m, a[e]);
      float g[8], s = 0.f;
#pragma unroll
      for (int e = 0; e < 8; ++e) { g[e] = expf(a[e] - m); s += g[e]; }
      float inv = 1.f / s;
#pragma unroll
      for (int e = 0; e < 8; ++e) g[e] *= inv;
      int i0 = 0; float v0 = g[0];
#pragma unroll
      for (int e = 1; e < 8; ++e) if (g[e] > v0) { v0 = g[e]; i0 = e; }
      int i1 = -1; float v1 = -1.f;
#pragma unroll
      for (int e = 0; e < 8; ++e) if (e != i0 && g[e] > v1) { v1 = g[e]; i1 = e; }
      float d = v0 + v1 + 1e-8f;
      int4 te; te.x = i0; te.y = i1;
      te.z = __float_as_int(v0 / d); te.w = __float_as_int(v1 / d);
      tokexp[t] = te;
      atomicAdd(&cnt[i0], 1); atomicAdd(&cnt[i1], 1);
    }
  }
  __syncthreads();
  if (tid < 8) atomicAdd(&counts[tid], cnt[tid]);
}

// ---------------------------------------------------------------------------
// Padded prefix offsets (256-row granularity) + rowblock(256)->expert map.
__global__ void k_offsets(const int* __restrict__ counts, int* __restrict__ offs,
                          int* __restrict__ rbStart, int* __restrict__ mapxp,
                          int* __restrict__ cursors)
{
  if (threadIdx.x == 0) {
    int off = 0, rb = 0;
    for (int e = 0; e < 8; ++e) {
      offs[e] = off; rbStart[e] = rb;
      int nrb = (counts[e] + 255) >> 8;
      off += nrb * 256;
      for (int i = 0; i < nrb; ++i) mapxp[rb++] = e;
    }
    offs[8] = off; rbStart[8] = rb;
    for (int i = rb; i < 512; ++i) mapxp[i] = -1;
  }
  if (threadIdx.x < 8) cursors[threadIdx.x] = 0;
}

// ---------------------------------------------------------------------------
// Assign each (token, slot) a compact row.
__global__ __launch_bounds__(256) void k_assign(
    const int4* __restrict__ tokexp, const int* __restrict__ offs,
    int* __restrict__ cursors, int* __restrict__ rowtab, float* __restrict__ roww)
{
  __shared__ int cnt[8], base[8];
  int tid = threadIdx.x;
  if (tid < 8) cnt[tid] = 0;
  __syncthreads();
  int t = blockIdx.x * 256 + tid;
  int4 te = tokexp[t];
  int ex0 = te.x, ex1 = te.y;
  int lr0 = atomicAdd(&cnt[ex0], 1);
  int lr1 = atomicAdd(&cnt[ex1], 1);
  __syncthreads();
  if (tid < 8) base[tid] = atomicAdd(&cursors[tid], cnt[tid]);
  __syncthreads();
  int row0 = offs[ex0] + base[ex0] + lr0;
  int row1 = offs[ex1] + base[ex1] + lr1;
  rowtab[row0] = t; roww[row0] = __int_as_float(te.z);
  rowtab[row1] = t; roww[row1] = __int_as_float(te.w);
}

// ---------------------------------------------------------------------------
// Transpose [K][N] fp32 -> [N][K] bf16 hi/lo planes (blockIdx.z = local expert).
__global__ __launch_bounds__(256) void k_tsplit(
    const float* __restrict__ in, unsigned short* __restrict__ oh,
    unsigned short* __restrict__ ol, int K, int N)
{
  __shared__ float lds[64][65];
  int e = blockIdx.z;
  int n0 = blockIdx.x * 64, k0 = blockIdx.y * 64;
  const float* ine = in + (size_t)e * K * N;
  unsigned short* ohe = oh + (size_t)e * N * K;
  unsigned short* ole = ol + (size_t)e * N * K;
  int tid = threadIdx.x;
#pragma unroll
  for (int i = 0; i < 8; ++i) {
    int idx = tid + i * 256;
    int r = idx >> 5, c2 = (idx & 31) * 2;
    float2 f = *(const float2*)(ine + (size_t)(k0 + r) * N + n0 + c2);
    lds[r][c2] = f.x; lds[r][c2 + 1] = f.y;
  }
  __syncthreads();
#pragma unroll
  for (int i = 0; i < 8; ++i) {
    int idx = tid + i * 256;
    int r = idx >> 5, c2 = (idx & 31) * 2;
    float a = lds[c2][r], b = lds[c2 + 1][r];
    ushort2 h2, l2;
    h2.x = f2bf_rne(a); l2.x = f2bf_rne(a - bf2f(h2.x));
    h2.y = f2bf_rne(b); l2.y = f2bf_rne(b - bf2f(h2.y));
    size_t o = (size_t)(n0 + r) * K + k0 + c2;
    *(ushort2*)(ohe + o) = h2;
    *(ushort2*)(ole + o) = l2;
  }
}

// ---------------------------------------------------------------------------
// 256^2 counted-vmcnt GEMM (m201-style), plain bf16 over virtual K' = 3K:
//   A' = [Ah | Ah | Al] along K, B' = [Bh | Bl | Bh]  => ah*bh + ah*bl + al*bh.
// 8 waves (2M x 4N, per-wave C = 128x64), BK=64, LDS dbuf 2 x (A 32K + B 32K).
// Stage: global_load_lds w=16 with pre-swizzled source (granule ^= row&7).
// Pipeline: 1 K-tile ahead, s_waitcnt vmcnt(8) (never 0 in loop), raw barriers,
// 4 phases/tile x 16 MFMA with setprio(1).
template <bool G1>
__global__ __launch_bounds__(512, 2) void k_gemm(
    const unsigned short* __restrict__ Ah, const unsigned short* __restrict__ Al,
    const unsigned short* __restrict__ Bh, const unsigned short* __restrict__ Bl,
    const int* __restrict__ rbStart, const int* __restrict__ mapxp,
    const int* __restrict__ rowtab, const float* __restrict__ bias,
    const float* __restrict__ roww,
    unsigned short* __restrict__ Hh, unsigned short* __restrict__ Hl,
    float* __restrict__ outp,
    int g, int epg, int sc, int ch)
{
  constexpr int K  = G1 ? D_IN : D_HID;       // per-plane reduction dim
  constexpr int NT = G1 ? D_HID : D_OUT;      // output cols per expert
  constexpr int NB = G1 ? (D_HID / 256) : (D_OUT / 256);
  constexpr int NK = 3 * K / 64;              // virtual k-tiles (48 / 96)

  int nwg = gridDim.x, orig = blockIdx.x;
  int wgid = (orig & 7) * (nwg >> 3) + (orig >> 3);   // XCD swizzle (nwg%8==0)
  int nb = wgid % NB, by = wgid / NB;

  int gbase = rbStart[g * epg], gend = rbStart[g * epg + epg];
  int rb = gbase + sc * ch + by;
  if (rb >= gend) return;
  int e = mapxp[rb];
  if (e < 0) return;
  int eL = e - g * epg;

  __shared__ unsigned short sA[2][256 * 64];
  __shared__ unsigned short sB[2][256 * 64];
  __shared__ float sbias[256], sw_[256];
  __shared__ int srt[256];

  int tid = threadIdx.x, lane = tid & 63, wave = tid >> 6;
  int wm = wave >> 2, wn = wave & 3;
  if (tid < 256) {
    sbias[tid] = bias[(size_t)e * NT + nb * 256 + tid];
    if constexpr (!G1) {
      sw_[tid] = roww[rb * 256 + tid];
      srt[tid] = rowtab[rb * 256 + tid];
    }
  }

  // staging address precompute: 4 A-granules + 4 B-granules (16B) per thread
  size_t aoff[4], boff[4];
  int ldst[4];
#pragma unroll
  for (int i = 0; i < 4; ++i) {
    int gdest = i * 512 + tid;            // granule index in [0, 2048)
    int row = gdest >> 3, gc = gdest & 7;
    int scg = (gc ^ (row & 7)) * 8;       // pre-swizzled source col (ushorts)
    if constexpr (G1) {
      int tok = rowtab[rb * 256 + row];
      aoff[i] = (size_t)tok * K + scg;
    } else {
      aoff[i] = ((size_t)(by * 256 + row)) * K + scg;   // chunk-local h rows
    }
    boff[i] = ((size_t)eL * NT + nb * 256 + row) * K + scg;
    ldst[i] = i * 4096 + wave * 512;      // wave-uniform LDS base (ushorts)
  }

  f32x4 acc[8][4];
#pragma unroll
  for (int mi = 0; mi < 8; ++mi)
#pragma unroll
    for (int nj = 0; nj < 4; ++nj) acc[mi][nj] = (f32x4){0.f, 0.f, 0.f, 0.f};

  auto ISSUE = [&](int kt, int buf) {
    const unsigned short* Ap; const unsigned short* Bp; int kcol;
    if constexpr (G1) {
      Ap = (kt < 32) ? Ah : Al;
      Bp = ((kt >> 4) == 1) ? Bl : Bh;
      kcol = (kt & 15) << 6;
    } else {
      Ap = (kt < 64) ? Ah : Al;
      Bp = ((kt >> 5) == 1) ? Bl : Bh;
      kcol = (kt & 31) << 6;
    }
#pragma unroll
    for (int i = 0; i < 4; ++i)
      __builtin_amdgcn_global_load_lds((const GLB_AS void*)(Ap + aoff[i] + kcol),
                                       (LDS_AS void*)(&sA[buf][ldst[i]]), 16, 0, 0);
#pragma unroll
    for (int i = 0; i < 4; ++i)
      __builtin_amdgcn_global_load_lds((const GLB_AS void*)(Bp + boff[i] + kcol),
                                       (LDS_AS void*)(&sB[buf][ldst[i]]), 16, 0, 0);
  };

  ISSUE(0, 0);   // prologue: 8 loads in flight
  for (int t = 0; t < NK; ++t) {
    int cur = t & 1;
    if (t + 1 < NK) {
      ISSUE(t + 1, cur ^ 1);
      asm volatile("s_waitcnt vmcnt(8)" ::: "memory");   // drain tile t only
    } else {
      asm volatile("s_waitcnt vmcnt(0)" ::: "memory");
    }
    __builtin_amdgcn_sched_barrier(0);
    __builtin_amdgcn_s_barrier();
    const unsigned short* A0 = &sA[cur][0];
    const unsigned short* B0 = &sB[cur][0];
#pragma unroll
    for (int ph = 0; ph < 4; ++ph) {
      const int mi0 = (ph >> 1) * 4, nj0 = (ph & 1) * 2;
      short8 af[4][2], bf[2][2];
#pragma unroll
      for (int mi = 0; mi < 4; ++mi)
#pragma unroll
        for (int kk = 0; kk < 2; ++kk) {
          int row = wm * 128 + (mi0 + mi) * 16 + (lane & 15);
          int co = ((kk * 4 + (lane >> 4)) ^ (lane & 7)) * 8;
          af[mi][kk] = *(const short8*)&A0[row * 64 + co];
        }
#pragma unroll
      for (int nj = 0; nj < 2; ++nj)
#pragma unroll
        for (int kk = 0; kk < 2; ++kk) {
          int row = wn * 64 + (nj0 + nj) * 16 + (lane & 15);
          int co = ((kk * 4 + (lane >> 4)) ^ (lane & 7)) * 8;
          bf[nj][kk] = *(const short8*)&B0[row * 64 + co];
        }
      __builtin_amdgcn_s_barrier();
      asm volatile("s_waitcnt lgkmcnt(0)" ::: "memory");
      __builtin_amdgcn_sched_barrier(0);
      __builtin_amdgcn_s_setprio(1);
#pragma unroll
      for (int kk = 0; kk < 2; ++kk)
#pragma unroll
        for (int mi = 0; mi < 4; ++mi)
#pragma unroll
          for (int nj = 0; nj < 2; ++nj)
            acc[mi0 + mi][nj0 + nj] = __builtin_amdgcn_mfma_f32_16x16x32_bf16(
                af[mi][kk], bf[nj][kk], acc[mi0 + mi][nj0 + nj], 0, 0, 0);
      __builtin_amdgcn_s_setprio(0);
      __builtin_amdgcn_s_barrier();
    }
  }

  // epilogue; C/D layout: col = lane&15, row = (lane>>4)*4 + r
#pragma unroll
  for (int mi = 0; mi < 8; ++mi)
#pragma unroll
    for (int nj = 0; nj < 4; ++nj) {
      int colL = wn * 64 + nj * 16 + (lane & 15);
#pragma unroll
      for (int r = 0; r < 4; ++r) {
        int rowL = wm * 128 + mi * 16 + (lane >> 4) * 4 + r;
        float v = acc[mi][nj][r] + sbias[colL];
        if constexpr (G1) {
          v = fmaxf(v, 0.f);
          uint32_t u = __builtin_bit_cast(uint32_t, v);
          unsigned short hi = (unsigned short)(u >> 16);
          float res = v - __builtin_bit_cast(float, u & 0xffff0000u);
          unsigned short lo = f2bf_rne(res);
          size_t o = ((size_t)by * 256 + rowL) * D_HID + nb * 256 + colL;
          Hh[o] = hi; Hl[o] = lo;
        } else {
          float w = sw_[rowL];
          if (w != 0.f)
            atomicAdd(outp + (size_t)srt[rowL] * D_OUT + nb * 256 + colL, v * w);
        }
      }
    }
}

// ---------------------------------------------------------------------------
extern "C" void kernel_launch(void* const* d_in, const int* in_sizes, int n_in,
                              void* d_out, int out_size, void* d_ws, size_t ws_size,
                              hipStream_t stream)
{
  const float* x  = (const float*)d_in[0];
  const float* gw = (const float*)d_in[1];
  const float* W1 = (const float*)d_in[2];
  const float* b1 = (const float*)d_in[3];
  const float* W2 = (const float*)d_in[4];
  const float* b2 = (const float*)d_in[5];
  float* out = (float*)d_out;
  (void)in_sizes; (void)n_in; (void)out_size;

  char* ws = (char*)d_ws;
  size_t o = 0;
  auto alloc = [&](size_t b) -> void* {
    void* p = ws + o; o += (b + 1023) & ~(size_t)1023; return p;
  };
  int*   counts  = (int*)alloc(1024);
  int*   cursors = (int*)alloc(1024);
  int*   offs    = (int*)alloc(1024);
  int*   rbStart = (int*)alloc(1024);
  int*   mapxp   = (int*)alloc(4096);
  int*   rowtab  = (int*)alloc(MAX_ROWS * 4);
  float* roww    = (float*)alloc(MAX_ROWS * 4);
  size_t zero_end = o;
  int4*  tokexp  = (int4*)alloc((size_t)T_TOKENS * 16);
  unsigned short* xs_hi = (unsigned short*)alloc((size_t)T_TOKENS * D_IN * 2);
  unsigned short* xs_lo = (unsigned short*)alloc((size_t)T_TOKENS * D_IN * 2);
  size_t small_end = o;

  // adaptive: EPG experts per weight-group, CH 256-row-blocks per h-chunk
  const size_t PER_EXP_W = ((size_t)D_IN * D_HID + (size_t)D_HID * D_OUT) * 2 * 2;
  const size_t PER_RB_H  = (size_t)256 * D_HID * 2 * 2;
  int EPG = 1, CH = 2;
  {
    int bestE = 0, bestC = 0;
    const int cands[4] = {8, 4, 2, 1};
    for (int ci = 0; ci < 4; ++ci) {
      int cand = cands[ci];
      size_t fixed = small_end + (size_t)cand * PER_EXP_W + (2u << 20);
      if (ws_size <= fixed + 2 * PER_RB_H) continue;
      size_t hav = ws_size - fixed;
      int wmax = cand * 64 < 128 + cand ? cand * 64 : 128 + cand;
      int chv = (int)(hav / PER_RB_H);
      if (chv > wmax + 1) chv = wmax + 1;
      chv &= ~1;
      if (chv < 2) continue;
      int goal = wmax < 80 ? wmax : 80;
      if (chv >= goal) { bestE = cand; bestC = chv; break; }
      if (chv > bestC) { bestE = cand; bestC = chv; }
    }
    if (bestE > 0) { EPG = bestE; CH = bestC; }
  }
  const int NGRP = 8 / EPG;
  const int WMAX = EPG * 64 < 128 + EPG ? EPG * 64 : 128 + EPG;
  const int NSC  = (WMAX + CH - 1) / CH;

  unsigned short* w1th = (unsigned short*)alloc((size_t)EPG * D_IN * D_HID * 2);
  unsigned short* w1tl = (unsigned short*)alloc((size_t)EPG * D_IN * D_HID * 2);
  unsigned short* w2th = (unsigned short*)alloc((size_t)EPG * D_HID * D_OUT * 2);
  unsigned short* w2tl = (unsigned short*)alloc((size_t)EPG * D_HID * D_OUT * 2);
  unsigned short* hh   = (unsigned short*)alloc((size_t)CH * 256 * D_HID * 2);
  unsigned short* hl   = (unsigned short*)alloc((size_t)CH * 256 * D_HID * 2);

  hipMemsetAsync(ws, 0, zero_end, stream);
  k_gate<<<T_TOKENS / 64, 256, 0, stream>>>(x, gw, xs_hi, xs_lo, out, tokexp, counts);
  k_offsets<<<1, 64, 0, stream>>>(counts, offs, rbStart, mapxp, cursors);
  k_assign<<<T_TOKENS / 256, 256, 0, stream>>>(tokexp, offs, cursors, rowtab, roww);

  for (int g = 0; g < NGRP; ++g) {
    k_tsplit<<<dim3(D_HID / 64, D_IN / 64, EPG), 256, 0, stream>>>(
        W1 + (size_t)g * EPG * D_IN * D_HID, w1th, w1tl, D_IN, D_HID);
    k_tsplit<<<dim3(D_OUT / 64, D_HID / 64, EPG), 256, 0, stream>>>(
        W2 + (size_t)g * EPG * D_HID * D_OUT, w2th, w2tl, D_HID, D_OUT);
    for (int sc = 0; sc < NSC; ++sc) {
      k_gemm<true><<<dim3(8 * CH), 512, 0, stream>>>(
          xs_hi, xs_lo, w1th, w1tl, rbStart, mapxp, rowtab, b1, roww,
          hh, hl, nullptr, g, EPG, sc, CH);
      k_gemm<false><<<dim3(4 * CH), 512, 0, stream>>>(
          hh, hl, w2th, w2tl, rbStart, mapxp, rowtab, b2, roww,
          nullptr, nullptr, out, g, EPG, sc, CH);
    }
  }
}

// Round 5
// 1315.672 us; speedup vs baseline: 3.2689x; 3.2689x over previous
//
#include <hip/hip_runtime.h>
#include <stdint.h>

#define T_TOKENS 16384
#define D_IN     1024
#define D_HID    2048
#define D_OUT    1024
#define N_EXP    8
#define MAX_ROWS 33792   // 2*T + 8*127 padded, rounded up

typedef short  short8  __attribute__((ext_vector_type(8)));
typedef float  f32x4   __attribute__((ext_vector_type(4)));

#define LDS_AS __attribute__((address_space(3)))
#define GLB_AS __attribute__((address_space(1)))

__device__ __forceinline__ unsigned short f2bf_rne(float f) {
  uint32_t u = __builtin_bit_cast(uint32_t, f);
  u += 0x7fff + ((u >> 16) & 1);
  return (unsigned short)(u >> 16);
}
__device__ __forceinline__ float bf2f(unsigned short h) {
  uint32_t u = ((uint32_t)h) << 16;
  return __builtin_bit_cast(float, u);
}
// truncation split of a pair of floats -> packed hi-word, lo-word (2 bf16 each)
__device__ __forceinline__ void split2(float a, float b, uint32_t& hw, uint32_t& lw) {
  uint32_t ua = __builtin_bit_cast(uint32_t, a);
  uint32_t ub = __builtin_bit_cast(uint32_t, b);
  hw = (ua >> 16) | (ub & 0xffff0000u);
  float ra = a - __builtin_bit_cast(float, ua & 0xffff0000u);
  float rb = b - __builtin_bit_cast(float, ub & 0xffff0000u);
  uint32_t ura = __builtin_bit_cast(uint32_t, ra);
  uint32_t urb = __builtin_bit_cast(uint32_t, rb);
  lw = (ura >> 16) | (urb & 0xffff0000u);
}

// ---------------------------------------------------------------------------
// Gate: fp32 logits -> softmax -> top2 -> renorm weights; expert histogram.
// Fused: residual init (out = x).
__global__ __launch_bounds__(256) void k_gate(
    const float* __restrict__ x, const float* __restrict__ gw,
    float* __restrict__ outp, int4* __restrict__ tokexp, int* __restrict__ counts)
{
  __shared__ float gwT[8][1024];
  __shared__ int cnt[8];
  int tid = threadIdx.x;
  if (tid < 8) cnt[tid] = 0;
  for (int i = tid; i < D_IN * N_EXP; i += 256) gwT[i & 7][i >> 3] = gw[i];
  __syncthreads();
  int wave = tid >> 6, lane = tid & 63;
  for (int tt = 0; tt < 16; ++tt) {
    int t = blockIdx.x * 64 + wave * 16 + tt;
    const float4* x4 = (const float4*)(x + (size_t)t * D_IN);
    float4 v[4];
#pragma unroll
    for (int j = 0; j < 4; ++j) v[j] = x4[j * 64 + lane];
    // residual init
#pragma unroll
    for (int j = 0; j < 4; ++j) {
      size_t off = (size_t)t * D_IN + (size_t)(j * 64 + lane) * 4;
      *(float4*)(outp + off) = v[j];
    }
    float a[8];
#pragma unroll
    for (int e = 0; e < 8; ++e) a[e] = 0.f;
#pragma unroll
    for (int e = 0; e < 8; ++e) {
#pragma unroll
      for (int j = 0; j < 4; ++j) {
        float4 g4 = ((const float4*)gwT[e])[j * 64 + lane];
        float* vp = (float*)&v[j];
        a[e] += vp[0] * g4.x + vp[1] * g4.y + vp[2] * g4.z + vp[3] * g4.w;
      }
    }
#pragma unroll
    for (int e = 0; e < 8; ++e) {
#pragma unroll
      for (int s = 32; s >= 1; s >>= 1) a[e] += __shfl_xor(a[e], s, 64);
    }
    if (lane == 0) {
      float m = a[0];
#pragma unroll
      for (int e = 1; e < 8; ++e) m = fmaxf(m, a[e]);
      float g[8], s = 0.f;
#pragma unroll
      for (int e = 0; e < 8; ++e) { g[e] = expf(a[e] - m); s += g[e]; }
      float inv = 1.f / s;
#pragma unroll
      for (int e = 0; e < 8; ++e) g[e] *= inv;
      int i0 = 0; float v0 = g[0];
#pragma unroll
      for (int e = 1; e < 8; ++e) if (g[e] > v0) { v0 = g[e]; i0 = e; }
      int i1 = -1; float v1 = -1.f;
#pragma unroll
      for (int e = 0; e < 8; ++e) if (e != i0 && g[e] > v1) { v1 = g[e]; i1 = e; }
      float d = v0 + v1 + 1e-8f;
      int4 te; te.x = i0; te.y = i1;
      te.z = __float_as_int(v0 / d); te.w = __float_as_int(v1 / d);
      tokexp[t] = te;
      atomicAdd(&cnt[i0], 1); atomicAdd(&cnt[i1], 1);
    }
  }
  __syncthreads();
  if (tid < 8) atomicAdd(&counts[tid], cnt[tid]);
}

// ---------------------------------------------------------------------------
// Padded prefix offsets (rows and row-blocks) + rowblock->expert map.
__global__ void k_offsets(const int* __restrict__ counts, int* __restrict__ offs,
                          int* __restrict__ rbStart, int* __restrict__ mapxp,
                          int* __restrict__ cursors)
{
  if (threadIdx.x == 0) {
    int off = 0, rb = 0;
    for (int e = 0; e < 8; ++e) {
      offs[e] = off; rbStart[e] = rb;
      int nrb = (counts[e] + 127) >> 7;
      off += nrb * 128;
      for (int i = 0; i < nrb; ++i) mapxp[rb++] = e;
    }
    offs[8] = off; rbStart[8] = rb;
    for (int i = rb; i < 1024; ++i) mapxp[i] = -1;
  }
  if (threadIdx.x < 8) cursors[threadIdx.x] = 0;
}

// ---------------------------------------------------------------------------
// Assign each (token, slot) a compact row.
__global__ __launch_bounds__(256) void k_assign(
    const int4* __restrict__ tokexp, const int* __restrict__ offs,
    int* __restrict__ cursors, int* __restrict__ rowtab, float* __restrict__ roww)
{
  __shared__ int cnt[8], base[8];
  int tid = threadIdx.x;
  if (tid < 8) cnt[tid] = 0;
  __syncthreads();
  int t = blockIdx.x * 256 + tid;
  int4 te = tokexp[t];
  int ex0 = te.x, ex1 = te.y;
  int lr0 = atomicAdd(&cnt[ex0], 1);
  int lr1 = atomicAdd(&cnt[ex1], 1);
  __syncthreads();
  if (tid < 8) base[tid] = atomicAdd(&cursors[tid], cnt[tid]);
  __syncthreads();
  int row0 = offs[ex0] + base[ex0] + lr0;
  int row1 = offs[ex1] + base[ex1] + lr1;
  rowtab[row0] = t; roww[row0] = __int_as_float(te.z);
  rowtab[row1] = t; roww[row1] = __int_as_float(te.w);
}

// ---------------------------------------------------------------------------
// Transpose [K][N] fp32 -> [N][K] bf16 hi/lo planes (blockIdx.z = local expert).
__global__ __launch_bounds__(256) void k_tsplit(
    const float* __restrict__ in, unsigned short* __restrict__ oh,
    unsigned short* __restrict__ ol, int K, int N)
{
  __shared__ float lds[64][65];
  int e = blockIdx.z;
  int n0 = blockIdx.x * 64, k0 = blockIdx.y * 64;
  const float* ine = in + (size_t)e * K * N;
  unsigned short* ohe = oh + (size_t)e * N * K;
  unsigned short* ole = ol + (size_t)e * N * K;
  int tid = threadIdx.x;
#pragma unroll
  for (int i = 0; i < 8; ++i) {
    int idx = tid + i * 256;
    int r = idx >> 5, c2 = (idx & 31) * 2;
    float2 f = *(const float2*)(ine + (size_t)(k0 + r) * N + n0 + c2);
    lds[r][c2] = f.x; lds[r][c2 + 1] = f.y;
  }
  __syncthreads();
#pragma unroll
  for (int i = 0; i < 8; ++i) {
    int idx = tid + i * 256;
    int r = idx >> 5, c2 = (idx & 31) * 2;
    float a = lds[c2][r], b = lds[c2 + 1][r];
    ushort2 h2, l2;
    h2.x = f2bf_rne(a); l2.x = f2bf_rne(a - bf2f(h2.x));
    h2.y = f2bf_rne(b); l2.y = f2bf_rne(b - bf2f(h2.y));
    size_t o = (size_t)(n0 + r) * K + k0 + c2;
    *(ushort2*)(ohe + o) = h2;
    *(ushort2*)(ole + o) = l2;
  }
}

// ---------------------------------------------------------------------------
// bf16x3 GEMM, 128x128 tile, BK=64, 4 waves (2x2 of 64x64), 16x16x32 MFMA.
// G1: A = x fp32 (gathered rows, reg-staged split). epi: relu -> h planes.
// G2: A = h planes (global_load_lds).            epi: *w -> atomicAdd(out).
// LDS granule-XOR swizzle: LDS[row][g] = src[row][g ^ (row&7)], granule=16B.
// PROVEN round-2 structure: 898 TF, MfmaUtil 37.8%, 0 bank conflicts. Do not
// edit the sync structure without a race-screened A/B.
template <bool G1>
__global__ __launch_bounds__(256, 2) void k_gemm(
    const float* __restrict__ xA,
    const unsigned short* __restrict__ hAh, const unsigned short* __restrict__ hAl,
    const unsigned short* __restrict__ Bh, const unsigned short* __restrict__ Bl,
    const int* __restrict__ rbStart, const int* __restrict__ mapxp,
    const int* __restrict__ rowtab, const float* __restrict__ bias,
    const float* __restrict__ roww,
    unsigned short* __restrict__ Hh, unsigned short* __restrict__ Hl,
    float* __restrict__ outp,
    int g, int epg, int sc, int ch_rb)
{
  constexpr int K  = G1 ? D_IN : D_HID;
  constexpr int NT = G1 ? D_HID : D_OUT;
  constexpr int NB = G1 ? (D_HID / 128) : (D_OUT / 128);

  // bijective XCD swizzle (grid is a multiple of 8)
  int nwg = gridDim.x, orig = blockIdx.x;
  int wgid = (orig & 7) * (nwg >> 3) + (orig >> 3);
  int nb = wgid % NB;
  int by = wgid / NB;

  int gbase = rbStart[g * epg], gend = rbStart[g * epg + epg];
  int rb = gbase + sc * ch_rb + by;
  if (rb >= gend) return;
  int e = mapxp[rb];
  if (e < 0) return;
  int eL = e - g * epg;

  __shared__ unsigned short sAh[128 * 64], sAl[128 * 64];
  __shared__ unsigned short sBh[128 * 64], sBl[128 * 64];
  __shared__ float sbias[128], sw[128];
  __shared__ int srowt[128];

  int tid = threadIdx.x, lane = tid & 63, wave = tid >> 6;
  int wm = wave >> 1, wn = wave & 1;
  if (tid < 128) {
    sbias[tid] = bias[(size_t)e * NT + nb * 128 + tid];
    if constexpr (!G1) {
      sw[tid] = roww[rb * 128 + tid];
      srowt[tid] = rowtab[rb * 128 + tid];
    }
  }

  int sgu = ((tid & 7) ^ ((tid >> 3) & 7)) * 8;  // pre-swizzled source granule
  size_t bbase[4];
#pragma unroll
  for (int i = 0; i < 4; ++i)
    bbase[i] = ((size_t)eL * NT + nb * 128 + i * 32 + (tid >> 3)) * K + sgu;

  size_t abase[4]; size_t srcb[2]; int arow[2], ag0[2];
  if constexpr (G1) {
    int cc = tid & 3;
#pragma unroll
    for (int it = 0; it < 2; ++it) {
      int rr = it * 64 + (tid >> 2);
      arow[it] = rr;
      ag0[it] = ((2 * cc) ^ (rr & 7)) * 8;
      int t = rowtab[rb * 128 + rr];
      srcb[it] = (size_t)t * D_IN + cc * 16;
    }
  } else {
#pragma unroll
    for (int i = 0; i < 4; ++i)
      abase[i] = ((size_t)by * 128 + i * 32 + (tid >> 3)) * D_HID + sgu;
  }

  f32x4 acc[4][4];
#pragma unroll
  for (int mi = 0; mi < 4; ++mi)
#pragma unroll
    for (int nj = 0; nj < 4; ++nj) acc[mi][nj] = (f32x4){0.f, 0.f, 0.f, 0.f};

  for (int kk = 0; kk < K; kk += 64) {
#pragma unroll
    for (int i = 0; i < 4; ++i) {
      int d = i * 2048 + wave * 512;
      __builtin_amdgcn_global_load_lds((const GLB_AS void*)(Bh + bbase[i] + kk),
                                       (LDS_AS void*)(&sBh[d]), 16, 0, 0);
      __builtin_amdgcn_global_load_lds((const GLB_AS void*)(Bl + bbase[i] + kk),
                                       (LDS_AS void*)(&sBl[d]), 16, 0, 0);
      if constexpr (!G1) {
        __builtin_amdgcn_global_load_lds((const GLB_AS void*)(hAh + abase[i] + kk),
                                         (LDS_AS void*)(&sAh[d]), 16, 0, 0);
        __builtin_amdgcn_global_load_lds((const GLB_AS void*)(hAl + abase[i] + kk),
                                         (LDS_AS void*)(&sAl[d]), 16, 0, 0);
      }
    }
    if constexpr (G1) {
#pragma unroll
      for (int it = 0; it < 2; ++it) {
        const float4* s = (const float4*)(xA + srcb[it] + kk);
        float4 f0 = s[0], f1 = s[1], f2 = s[2], f3 = s[3];
        uint4 H0, L0, H1, L1;
        split2(f0.x, f0.y, H0.x, L0.x); split2(f0.z, f0.w, H0.y, L0.y);
        split2(f1.x, f1.y, H0.z, L0.z); split2(f1.z, f1.w, H0.w, L0.w);
        split2(f2.x, f2.y, H1.x, L1.x); split2(f2.z, f2.w, H1.y, L1.y);
        split2(f3.x, f3.y, H1.z, L1.z); split2(f3.z, f3.w, H1.w, L1.w);
        int wo = arow[it] * 64;
        *(uint4*)&sAh[wo + ag0[it]]       = H0;
        *(uint4*)&sAh[wo + (ag0[it] ^ 8)] = H1;
        *(uint4*)&sAl[wo + ag0[it]]       = L0;
        *(uint4*)&sAl[wo + (ag0[it] ^ 8)] = L1;
      }
    }
    asm volatile("s_waitcnt vmcnt(0)" ::: "memory");
    __syncthreads();
#pragma unroll
    for (int kh = 0; kh < 2; ++kh) {
      int co = ((kh * 4 + (lane >> 4)) ^ (lane & 7)) * 8;
      short8 a_h[4], a_l[4];
#pragma unroll
      for (int mi = 0; mi < 4; ++mi) {
        int row = wm * 64 + mi * 16 + (lane & 15);
        a_h[mi] = *(const short8*)&sAh[row * 64 + co];
        a_l[mi] = *(const short8*)&sAl[row * 64 + co];
      }
#pragma unroll
      for (int nj = 0; nj < 4; ++nj) {
        int rowb = wn * 64 + nj * 16 + (lane & 15);
        short8 b_h = *(const short8*)&sBh[rowb * 64 + co];
        short8 b_l = *(const short8*)&sBl[rowb * 64 + co];
#pragma unroll
        for (int mi = 0; mi < 4; ++mi) {
          acc[mi][nj] = __builtin_amdgcn_mfma_f32_16x16x32_bf16(a_h[mi], b_h, acc[mi][nj], 0, 0, 0);
          acc[mi][nj] = __builtin_amdgcn_mfma_f32_16x16x32_bf16(a_h[mi], b_l, acc[mi][nj], 0, 0, 0);
          acc[mi][nj] = __builtin_amdgcn_mfma_f32_16x16x32_bf16(a_l[mi], b_h, acc[mi][nj], 0, 0, 0);
        }
      }
    }
    __syncthreads();
  }
  // epilogue; C/D layout: col = lane&15, row = (lane>>4)*4 + r
#pragma unroll
  for (int mi = 0; mi < 4; ++mi)
#pragma unroll
    for (int nj = 0; nj < 4; ++nj) {
      int colL = wn * 64 + nj * 16 + (lane & 15);
#pragma unroll
      for (int r = 0; r < 4; ++r) {
        int rowL = wm * 64 + mi * 16 + (lane >> 4) * 4 + r;
        float v = acc[mi][nj][r] + sbias[colL];
        if constexpr (G1) {
          v = fmaxf(v, 0.f);
          uint32_t u = __builtin_bit_cast(uint32_t, v);
          unsigned short hi = (unsigned short)(u >> 16);
          float res = v - __builtin_bit_cast(float, u & 0xffff0000u);
          unsigned short lo = (unsigned short)(__builtin_bit_cast(uint32_t, res) >> 16);
          size_t o = ((size_t)by * 128 + rowL) * D_HID + nb * 128 + colL;
          Hh[o] = hi; Hl[o] = lo;
        } else {
          float w = sw[rowL];
          if (w != 0.f)
            atomicAdd(outp + (size_t)srowt[rowL] * D_OUT + nb * 128 + colL, v * w);
        }
      }
    }
}

// ---------------------------------------------------------------------------
extern "C" void kernel_launch(void* const* d_in, const int* in_sizes, int n_in,
                              void* d_out, int out_size, void* d_ws, size_t ws_size,
                              hipStream_t stream)
{
  const float* x  = (const float*)d_in[0];
  const float* gw = (const float*)d_in[1];
  const float* W1 = (const float*)d_in[2];
  const float* b1 = (const float*)d_in[3];
  const float* W2 = (const float*)d_in[4];
  const float* b2 = (const float*)d_in[5];
  float* out = (float*)d_out;
  (void)in_sizes; (void)n_in; (void)out_size;

  char* ws = (char*)d_ws;
  size_t o = 0;
  auto alloc = [&](size_t b) -> void* {
    void* p = ws + o; o += (b + 1023) & ~(size_t)1023; return p;
  };
  int*   counts  = (int*)alloc(1024);
  int*   cursors = (int*)alloc(1024);
  int*   offs    = (int*)alloc(1024);
  int*   rbStart = (int*)alloc(1024);
  int*   mapxp   = (int*)alloc(4096);
  int*   rowtab  = (int*)alloc(MAX_ROWS * 4);
  float* roww    = (float*)alloc(MAX_ROWS * 4);
  size_t zero_end = o;
  int4*  tokexp  = (int4*)alloc((size_t)T_TOKENS * 16);
  size_t small_end = o;

  // adaptive sizing: EPG experts per weight-group, CH row-blocks per h-chunk
  const size_t PER_EXP_W = ((size_t)D_IN * D_HID + (size_t)D_HID * D_OUT) * 2 * 2; // hi+lo bytes
  const size_t PER_RB_H  = (size_t)128 * D_HID * 2 * 2;                            // hi+lo bytes
  int EPG = 1, CH = 1;
  {
    int bestE = 0, bestC = 0;
    const int cands[4] = {8, 4, 2, 1};
    for (int ci = 0; ci < 4; ++ci) {
      int cand = cands[ci];
      size_t fixed = small_end + (size_t)cand * PER_EXP_W + (1u << 20);
      if (ws_size <= fixed + PER_RB_H) continue;
      size_t hav = ws_size - fixed;
      int wmax = (cand * 128 < 256 + cand) ? cand * 128 : 256 + cand;
      int ch = (int)(hav / PER_RB_H);
      if (ch > wmax) ch = wmax;
      int goal = wmax < 33 ? wmax : 33;
      if (ch >= goal) { bestE = cand; bestC = ch; break; }
      if (ch > bestC) { bestE = cand; bestC = ch; }
    }
    if (bestE > 0) { EPG = bestE; CH = bestC; }
  }
  const int NGRP = 8 / EPG;
  const int WMAX = (EPG * 128 < 256 + EPG) ? EPG * 128 : 256 + EPG;
  const int NSC  = (WMAX + CH - 1) / CH;

  unsigned short* w1th = (unsigned short*)alloc((size_t)EPG * D_IN * D_HID * 2);
  unsigned short* w1tl = (unsigned short*)alloc((size_t)EPG * D_IN * D_HID * 2);
  unsigned short* w2th = (unsigned short*)alloc((size_t)EPG * D_HID * D_OUT * 2);
  unsigned short* w2tl = (unsigned short*)alloc((size_t)EPG * D_HID * D_OUT * 2);
  unsigned short* hh   = (unsigned short*)alloc((size_t)CH * 128 * D_HID * 2);
  unsigned short* hl   = (unsigned short*)alloc((size_t)CH * 128 * D_HID * 2);

  hipMemsetAsync(ws, 0, zero_end, stream);
  k_gate<<<T_TOKENS / 64, 256, 0, stream>>>(x, gw, out, tokexp, counts);
  k_offsets<<<1, 64, 0, stream>>>(counts, offs, rbStart, mapxp, cursors);
  k_assign<<<T_TOKENS / 256, 256, 0, stream>>>(tokexp, offs, cursors, rowtab, roww);

  for (int g = 0; g < NGRP; ++g) {
    k_tsplit<<<dim3(D_HID / 64, D_IN / 64, EPG), 256, 0, stream>>>(
        W1 + (size_t)g * EPG * D_IN * D_HID, w1th, w1tl, D_IN, D_HID);
    k_tsplit<<<dim3(D_OUT / 64, D_HID / 64, EPG), 256, 0, stream>>>(
        W2 + (size_t)g * EPG * D_HID * D_OUT, w2th, w2tl, D_HID, D_OUT);
    for (int sc = 0; sc < NSC; ++sc) {
      k_gemm<true><<<dim3(16 * CH), 256, 0, stream>>>(
          x, nullptr, nullptr, w1th, w1tl, rbStart, mapxp, rowtab, b1, roww,
          hh, hl, nullptr, g, EPG, sc, CH);
      k_gemm<false><<<dim3(8 * CH), 256, 0, stream>>>(
          nullptr, hh, hl, w2th, w2tl, rbStart, mapxp, rowtab, b2, roww,
          nullptr, nullptr, out, g, EPG, sc, CH);
    }
  }
}

// Round 6
// 1125.531 us; speedup vs baseline: 3.8211x; 1.1689x over previous
//
#include <hip/hip_runtime.h>
#include <stdint.h>

#define T_TOKENS 16384
#define D_IN     1024
#define D_HID    2048
#define D_OUT    1024
#define N_EXP    8
#define MAX_ROWS 33792   // 2*T + 8*127 padded, rounded up

typedef short  short8  __attribute__((ext_vector_type(8)));
typedef float  f32x4   __attribute__((ext_vector_type(4)));

#define LDS_AS __attribute__((address_space(3)))
#define GLB_AS __attribute__((address_space(1)))

__device__ __forceinline__ unsigned short f2bf_rne(float f) {
  uint32_t u = __builtin_bit_cast(uint32_t, f);
  u += 0x7fff + ((u >> 16) & 1);
  return (unsigned short)(u >> 16);
}
__device__ __forceinline__ float bf2f(unsigned short h) {
  uint32_t u = ((uint32_t)h) << 16;
  return __builtin_bit_cast(float, u);
}
// truncation split of a pair of floats -> packed hi-word, lo-word (2 bf16 each)
__device__ __forceinline__ void split2(float a, float b, uint32_t& hw, uint32_t& lw) {
  uint32_t ua = __builtin_bit_cast(uint32_t, a);
  uint32_t ub = __builtin_bit_cast(uint32_t, b);
  hw = (ua >> 16) | (ub & 0xffff0000u);
  float ra = a - __builtin_bit_cast(float, ua & 0xffff0000u);
  float rb = b - __builtin_bit_cast(float, ub & 0xffff0000u);
  uint32_t ura = __builtin_bit_cast(uint32_t, ra);
  uint32_t urb = __builtin_bit_cast(uint32_t, rb);
  lw = (ura >> 16) | (urb & 0xffff0000u);
}

// ---------------------------------------------------------------------------
// Gate: fp32 logits -> softmax -> top2 -> renorm weights; expert histogram.
// Fused: residual init (out = x).
__global__ __launch_bounds__(256) void k_gate(
    const float* __restrict__ x, const float* __restrict__ gw,
    float* __restrict__ outp, int4* __restrict__ tokexp, int* __restrict__ counts)
{
  __shared__ float gwT[8][1024];
  __shared__ int cnt[8];
  int tid = threadIdx.x;
  if (tid < 8) cnt[tid] = 0;
  for (int i = tid; i < D_IN * N_EXP; i += 256) gwT[i & 7][i >> 3] = gw[i];
  __syncthreads();
  int wave = tid >> 6, lane = tid & 63;
  for (int tt = 0; tt < 16; ++tt) {
    int t = blockIdx.x * 64 + wave * 16 + tt;
    const float4* x4 = (const float4*)(x + (size_t)t * D_IN);
    float4 v[4];
#pragma unroll
    for (int j = 0; j < 4; ++j) v[j] = x4[j * 64 + lane];
    // residual init
#pragma unroll
    for (int j = 0; j < 4; ++j) {
      size_t off = (size_t)t * D_IN + (size_t)(j * 64 + lane) * 4;
      *(float4*)(outp + off) = v[j];
    }
    float a[8];
#pragma unroll
    for (int e = 0; e < 8; ++e) a[e] = 0.f;
#pragma unroll
    for (int e = 0; e < 8; ++e) {
#pragma unroll
      for (int j = 0; j < 4; ++j) {
        float4 g4 = ((const float4*)gwT[e])[j * 64 + lane];
        float* vp = (float*)&v[j];
        a[e] += vp[0] * g4.x + vp[1] * g4.y + vp[2] * g4.z + vp[3] * g4.w;
      }
    }
#pragma unroll
    for (int e = 0; e < 8; ++e) {
#pragma unroll
      for (int s = 32; s >= 1; s >>= 1) a[e] += __shfl_xor(a[e], s, 64);
    }
    if (lane == 0) {
      float m = a[0];
#pragma unroll
      for (int e = 1; e < 8; ++e) m = fmaxf(m, a[e]);
      float g[8], s = 0.f;
#pragma unroll
      for (int e = 0; e < 8; ++e) { g[e] = expf(a[e] - m); s += g[e]; }
      float inv = 1.f / s;
#pragma unroll
      for (int e = 0; e < 8; ++e) g[e] *= inv;
      int i0 = 0; float v0 = g[0];
#pragma unroll
      for (int e = 1; e < 8; ++e) if (g[e] > v0) { v0 = g[e]; i0 = e; }
      int i1 = -1; float v1 = -1.f;
#pragma unroll
      for (int e = 0; e < 8; ++e) if (e != i0 && g[e] > v1) { v1 = g[e]; i1 = e; }
      float d = v0 + v1 + 1e-8f;
      int4 te; te.x = i0; te.y = i1;
      te.z = __float_as_int(v0 / d); te.w = __float_as_int(v1 / d);
      tokexp[t] = te;
      atomicAdd(&cnt[i0], 1); atomicAdd(&cnt[i1], 1);
    }
  }
  __syncthreads();
  if (tid < 8) atomicAdd(&counts[tid], cnt[tid]);
}

// ---------------------------------------------------------------------------
// Padded prefix offsets + rowblock->expert map. Parallel mapxp fill
// (round-5's single-thread 1300-store loop was a serial-latency suspect).
__global__ void k_offsets(const int* __restrict__ counts, int* __restrict__ offs,
                          int* __restrict__ rbStart, int* __restrict__ mapxp,
                          int* __restrict__ cursors)
{
  __shared__ int s_rb[9], s_off[9];
  int tid = threadIdx.x;
  if (tid == 0) {
    int off = 0, rb = 0;
    for (int e = 0; e < 8; ++e) {
      s_off[e] = off; s_rb[e] = rb;
      int nrb = (counts[e] + 127) >> 7;
      off += nrb * 128; rb += nrb;
    }
    s_off[8] = off; s_rb[8] = rb;
  }
  __syncthreads();
  if (tid < 9) { offs[tid] = s_off[tid]; rbStart[tid] = s_rb[tid]; }
  if (tid < 8) cursors[tid] = 0;
  for (int i = tid; i < 1024; i += 64) {
    int v = -1;
#pragma unroll
    for (int e = 0; e < 8; ++e) if (i >= s_rb[e] && i < s_rb[e + 1]) v = e;
    mapxp[i] = v;
  }
}

// ---------------------------------------------------------------------------
// Assign each (token, slot) a compact row.
__global__ __launch_bounds__(256) void k_assign(
    const int4* __restrict__ tokexp, const int* __restrict__ offs,
    int* __restrict__ cursors, int* __restrict__ rowtab, float* __restrict__ roww)
{
  __shared__ int cnt[8], base[8];
  int tid = threadIdx.x;
  if (tid < 8) cnt[tid] = 0;
  __syncthreads();
  int t = blockIdx.x * 256 + tid;
  int4 te = tokexp[t];
  int ex0 = te.x, ex1 = te.y;
  int lr0 = atomicAdd(&cnt[ex0], 1);
  int lr1 = atomicAdd(&cnt[ex1], 1);
  __syncthreads();
  if (tid < 8) base[tid] = atomicAdd(&cursors[tid], cnt[tid]);
  __syncthreads();
  int row0 = offs[ex0] + base[ex0] + lr0;
  int row1 = offs[ex1] + base[ex1] + lr1;
  rowtab[row0] = t; roww[row0] = __int_as_float(te.z);
  rowtab[row1] = t; roww[row1] = __int_as_float(te.w);
}

// ---------------------------------------------------------------------------
// Transpose [K][N] fp32 -> [N][K] bf16 hi/lo planes (blockIdx.z = local expert).
__global__ __launch_bounds__(256) void k_tsplit(
    const float* __restrict__ in, unsigned short* __restrict__ oh,
    unsigned short* __restrict__ ol, int K, int N)
{
  __shared__ float lds[64][65];
  int e = blockIdx.z;
  int n0 = blockIdx.x * 64, k0 = blockIdx.y * 64;
  const float* ine = in + (size_t)e * K * N;
  unsigned short* ohe = oh + (size_t)e * N * K;
  unsigned short* ole = ol + (size_t)e * N * K;
  int tid = threadIdx.x;
#pragma unroll
  for (int i = 0; i < 8; ++i) {
    int idx = tid + i * 256;
    int r = idx >> 5, c2 = (idx & 31) * 2;
    float2 f = *(const float2*)(ine + (size_t)(k0 + r) * N + n0 + c2);
    lds[r][c2] = f.x; lds[r][c2 + 1] = f.y;
  }
  __syncthreads();
#pragma unroll
  for (int i = 0; i < 8; ++i) {
    int idx = tid + i * 256;
    int r = idx >> 5, c2 = (idx & 31) * 2;
    float a = lds[c2][r], b = lds[c2 + 1][r];
    ushort2 h2, l2;
    h2.x = f2bf_rne(a); l2.x = f2bf_rne(a - bf2f(h2.x));
    h2.y = f2bf_rne(b); l2.y = f2bf_rne(b - bf2f(h2.y));
    size_t o = (size_t)(n0 + r) * K + k0 + c2;
    *(ushort2*)(ohe + o) = h2;
    *(ushort2*)(ole + o) = l2;
  }
}

// ---------------------------------------------------------------------------
// GEMM, 128x128 tile, BK=64, 4 waves (2x2 of 64x64), 16x16x32 MFMA.
// G1 (bf16x3): A = x fp32 (gathered, reg-staged hi/lo). epi: relu -> h hi
//              (RNE) only.   terms: ah*bh + ah*bl + al*bh.
// G2 (bf16x2): A = h hi plane (global_load_lds), no A-lo. epi: *w ->
//              atomicAdd(out).   terms: ah*bh + ah*bl.
// LDS granule-XOR swizzle: LDS[row][g] = src[row][g ^ (row&7)], granule=16B.
// PROVEN round-2/5 sync structure: ~920 TF, MfmaUtil 39%, 0 bank conflicts.
// Do not edit the sync structure without a race-screened A/B.
template <bool G1>
__global__ __launch_bounds__(256, G1 ? 2 : 3) void k_gemm(
    const float* __restrict__ xA, const unsigned short* __restrict__ hA,
    const unsigned short* __restrict__ Bh, const unsigned short* __restrict__ Bl,
    const int* __restrict__ rbStart, const int* __restrict__ mapxp,
    const int* __restrict__ rowtab, const float* __restrict__ bias,
    const float* __restrict__ roww,
    unsigned short* __restrict__ Hh, float* __restrict__ outp,
    int g, int epg, int sc, int ch_rb)
{
  constexpr int K  = G1 ? D_IN : D_HID;
  constexpr int NT = G1 ? D_HID : D_OUT;
  constexpr int NB = G1 ? (D_HID / 128) : (D_OUT / 128);

  // bijective XCD swizzle (grid is a multiple of 8)
  int nwg = gridDim.x, orig = blockIdx.x;
  int wgid = (orig & 7) * (nwg >> 3) + (orig >> 3);
  int nb = wgid % NB;
  int by = wgid / NB;

  int gbase = rbStart[g * epg], gend = rbStart[g * epg + epg];
  int rb = gbase + sc * ch_rb + by;
  if (rb >= gend) return;
  int e = mapxp[rb];
  if (e < 0) return;
  int eL = e - g * epg;

  __shared__ unsigned short sAh[128 * 64];
  __shared__ unsigned short sAl[G1 ? 128 * 64 : 64];   // G2: no A-lo plane
  __shared__ unsigned short sBh[128 * 64], sBl[128 * 64];
  __shared__ float sbias[128], sw[128];
  __shared__ int srowt[128];

  int tid = threadIdx.x, lane = tid & 63, wave = tid >> 6;
  int wm = wave >> 1, wn = wave & 1;
  if (tid < 128) {
    sbias[tid] = bias[(size_t)e * NT + nb * 128 + tid];
    if constexpr (!G1) {
      sw[tid] = roww[rb * 128 + tid];
      srowt[tid] = rowtab[rb * 128 + tid];
    }
  }

  int sgu = ((tid & 7) ^ ((tid >> 3) & 7)) * 8;  // pre-swizzled source granule
  size_t bbase[4];
#pragma unroll
  for (int i = 0; i < 4; ++i)
    bbase[i] = ((size_t)eL * NT + nb * 128 + i * 32 + (tid >> 3)) * K + sgu;

  size_t abase[4]; size_t srcb[2]; int arow[2], ag0[2];
  if constexpr (G1) {
    int cc = tid & 3;
#pragma unroll
    for (int it = 0; it < 2; ++it) {
      int rr = it * 64 + (tid >> 2);
      arow[it] = rr;
      ag0[it] = ((2 * cc) ^ (rr & 7)) * 8;
      int t = rowtab[rb * 128 + rr];
      srcb[it] = (size_t)t * D_IN + cc * 16;
    }
  } else {
#pragma unroll
    for (int i = 0; i < 4; ++i)
      abase[i] = ((size_t)by * 128 + i * 32 + (tid >> 3)) * D_HID + sgu;
  }

  f32x4 acc[4][4];
#pragma unroll
  for (int mi = 0; mi < 4; ++mi)
#pragma unroll
    for (int nj = 0; nj < 4; ++nj) acc[mi][nj] = (f32x4){0.f, 0.f, 0.f, 0.f};

  for (int kk = 0; kk < K; kk += 64) {
#pragma unroll
    for (int i = 0; i < 4; ++i) {
      int d = i * 2048 + wave * 512;
      __builtin_amdgcn_global_load_lds((const GLB_AS void*)(Bh + bbase[i] + kk),
                                       (LDS_AS void*)(&sBh[d]), 16, 0, 0);
      __builtin_amdgcn_global_load_lds((const GLB_AS void*)(Bl + bbase[i] + kk),
                                       (LDS_AS void*)(&sBl[d]), 16, 0, 0);
      if constexpr (!G1) {
        __builtin_amdgcn_global_load_lds((const GLB_AS void*)(hA + abase[i] + kk),
                                         (LDS_AS void*)(&sAh[d]), 16, 0, 0);
      }
    }
    if constexpr (G1) {
#pragma unroll
      for (int it = 0; it < 2; ++it) {
        const float4* s = (const float4*)(xA + srcb[it] + kk);
        float4 f0 = s[0], f1 = s[1], f2 = s[2], f3 = s[3];
        uint4 H0, L0, H1, L1;
        split2(f0.x, f0.y, H0.x, L0.x); split2(f0.z, f0.w, H0.y, L0.y);
        split2(f1.x, f1.y, H0.z, L0.z); split2(f1.z, f1.w, H0.w, L0.w);
        split2(f2.x, f2.y, H1.x, L1.x); split2(f2.z, f2.w, H1.y, L1.y);
        split2(f3.x, f3.y, H1.z, L1.z); split2(f3.z, f3.w, H1.w, L1.w);
        int wo = arow[it] * 64;
        *(uint4*)&sAh[wo + ag0[it]]       = H0;
        *(uint4*)&sAh[wo + (ag0[it] ^ 8)] = H1;
        *(uint4*)&sAl[wo + ag0[it]]       = L0;
        *(uint4*)&sAl[wo + (ag0[it] ^ 8)] = L1;
      }
    }
    asm volatile("s_waitcnt vmcnt(0)" ::: "memory");
    __syncthreads();
#pragma unroll
    for (int kh = 0; kh < 2; ++kh) {
      int co = ((kh * 4 + (lane >> 4)) ^ (lane & 7)) * 8;
      short8 a_h[4], a_l[4];
#pragma unroll
      for (int mi = 0; mi < 4; ++mi) {
        int row = wm * 64 + mi * 16 + (lane & 15);
        a_h[mi] = *(const short8*)&sAh[row * 64 + co];
        if constexpr (G1) a_l[mi] = *(const short8*)&sAl[row * 64 + co];
      }
#pragma unroll
      for (int nj = 0; nj < 4; ++nj) {
        int rowb = wn * 64 + nj * 16 + (lane & 15);
        short8 b_h = *(const short8*)&sBh[rowb * 64 + co];
        short8 b_l = *(const short8*)&sBl[rowb * 64 + co];
#pragma unroll
        for (int mi = 0; mi < 4; ++mi) {
          acc[mi][nj] = __builtin_amdgcn_mfma_f32_16x16x32_bf16(a_h[mi], b_h, acc[mi][nj], 0, 0, 0);
          acc[mi][nj] = __builtin_amdgcn_mfma_f32_16x16x32_bf16(a_h[mi], b_l, acc[mi][nj], 0, 0, 0);
          if constexpr (G1)
            acc[mi][nj] = __builtin_amdgcn_mfma_f32_16x16x32_bf16(a_l[mi], b_h, acc[mi][nj], 0, 0, 0);
        }
      }
    }
    __syncthreads();
  }
  // epilogue; C/D layout: col = lane&15, row = (lane>>4)*4 + r
#pragma unroll
  for (int mi = 0; mi < 4; ++mi)
#pragma unroll
    for (int nj = 0; nj < 4; ++nj) {
      int colL = wn * 64 + nj * 16 + (lane & 15);
#pragma unroll
      for (int r = 0; r < 4; ++r) {
        int rowL = wm * 64 + mi * 16 + (lane >> 4) * 4 + r;
        float v = acc[mi][nj][r] + sbias[colL];
        if constexpr (G1) {
          v = fmaxf(v, 0.f);
          size_t o = ((size_t)by * 128 + rowL) * D_HID + nb * 128 + colL;
          Hh[o] = f2bf_rne(v);                 // RNE hi only (bf16x2 G2)
        } else {
          float w = sw[rowL];
          if (w != 0.f)
            atomicAdd(outp + (size_t)srowt[rowL] * D_OUT + nb * 128 + colL, v * w);
        }
      }
    }
}

// ---------------------------------------------------------------------------
extern "C" void kernel_launch(void* const* d_in, const int* in_sizes, int n_in,
                              void* d_out, int out_size, void* d_ws, size_t ws_size,
                              hipStream_t stream)
{
  const float* x  = (const float*)d_in[0];
  const float* gw = (const float*)d_in[1];
  const float* W1 = (const float*)d_in[2];
  const float* b1 = (const float*)d_in[3];
  const float* W2 = (const float*)d_in[4];
  const float* b2 = (const float*)d_in[5];
  float* out = (float*)d_out;
  (void)in_sizes; (void)n_in; (void)out_size;

  char* ws = (char*)d_ws;
  size_t o = 0;
  auto alloc = [&](size_t b) -> void* {
    void* p = ws + o; o += (b + 1023) & ~(size_t)1023; return p;
  };
  int*   counts  = (int*)alloc(1024);
  int*   cursors = (int*)alloc(1024);
  int*   offs    = (int*)alloc(1024);
  int*   rbStart = (int*)alloc(1024);
  int*   mapxp   = (int*)alloc(4096);
  int*   rowtab  = (int*)alloc(MAX_ROWS * 4);
  float* roww    = (float*)alloc(MAX_ROWS * 4);
  size_t zero_end = o;
  int4*  tokexp  = (int4*)alloc((size_t)T_TOKENS * 16);
  size_t small_end = o;

  // adaptive sizing: EPG experts per weight-group, CH row-blocks per h-chunk
  const size_t PER_EXP_W = ((size_t)D_IN * D_HID + (size_t)D_HID * D_OUT) * 2 * 2; // hi+lo bytes
  const size_t PER_RB_H  = (size_t)128 * D_HID * 2;                                // hi-only bytes
  int EPG = 1, CH = 1;
  {
    int bestE = 0, bestC = 0;
    const int cands[4] = {8, 4, 2, 1};
    for (int ci = 0; ci < 4; ++ci) {
      int cand = cands[ci];
      size_t fixed = small_end + (size_t)cand * PER_EXP_W + (1u << 20);
      if (ws_size <= fixed + PER_RB_H) continue;
      size_t hav = ws_size - fixed;
      int wmax = (cand * 128 < 256 + cand) ? cand * 128 : 256 + cand;
      int ch = (int)(hav / PER_RB_H);
      if (ch > wmax) ch = wmax;
      int goal = wmax < 33 ? wmax : 33;
      if (ch >= goal) { bestE = cand; bestC = ch; break; }
      if (ch > bestC) { bestE = cand; bestC = ch; }
    }
    if (bestE > 0) { EPG = bestE; CH = bestC; }
  }
  const int NGRP = 8 / EPG;
  const int WMAX = (EPG * 128 < 256 + EPG) ? EPG * 128 : 256 + EPG;
  const int NSC  = (WMAX + CH - 1) / CH;

  unsigned short* w1th = (unsigned short*)alloc((size_t)EPG * D_IN * D_HID * 2);
  unsigned short* w1tl = (unsigned short*)alloc((size_t)EPG * D_IN * D_HID * 2);
  unsigned short* w2th = (unsigned short*)alloc((size_t)EPG * D_HID * D_OUT * 2);
  unsigned short* w2tl = (unsigned short*)alloc((size_t)EPG * D_HID * D_OUT * 2);
  unsigned short* hh   = (unsigned short*)alloc((size_t)CH * 128 * D_HID * 2);

  hipMemsetAsync(ws, 0, zero_end, stream);
  k_gate<<<T_TOKENS / 64, 256, 0, stream>>>(x, gw, out, tokexp, counts);
  k_offsets<<<1, 64, 0, stream>>>(counts, offs, rbStart, mapxp, cursors);
  k_assign<<<T_TOKENS / 256, 256, 0, stream>>>(tokexp, offs, cursors, rowtab, roww);

  for (int g = 0; g < NGRP; ++g) {
    k_tsplit<<<dim3(D_HID / 64, D_IN / 64, EPG), 256, 0, stream>>>(
        W1 + (size_t)g * EPG * D_IN * D_HID, w1th, w1tl, D_IN, D_HID);
    k_tsplit<<<dim3(D_OUT / 64, D_HID / 64, EPG), 256, 0, stream>>>(
        W2 + (size_t)g * EPG * D_HID * D_OUT, w2th, w2tl, D_HID, D_OUT);
    for (int sc = 0; sc < NSC; ++sc) {
      k_gemm<true><<<dim3(16 * CH), 256, 0, stream>>>(
          x, nullptr, w1th, w1tl, rbStart, mapxp, rowtab, b1, roww,
          hh, nullptr, g, EPG, sc, CH);
      k_gemm<false><<<dim3(8 * CH), 256, 0, stream>>>(
          nullptr, hh, w2th, w2tl, rbStart, mapxp, rowtab, b2, roww,
          nullptr, out, g, EPG, sc, CH);
    }
  }
}

// Round 7
// 1029.185 us; speedup vs baseline: 4.1788x; 1.0936x over previous
//
#include <hip/hip_runtime.h>
#include <stdint.h>

#define T_TOKENS 16384
#define D_IN     1024
#define D_HID    2048
#define D_OUT    1024
#define N_EXP    8
#define MAX_ROWS 33792   // 2*T + 8*127 padded, rounded up

typedef short  short8  __attribute__((ext_vector_type(8)));
typedef float  f32x4   __attribute__((ext_vector_type(4)));

#define LDS_AS __attribute__((address_space(3)))
#define GLB_AS __attribute__((address_space(1)))

__device__ __forceinline__ unsigned short f2bf_rne(float f) {
  uint32_t u = __builtin_bit_cast(uint32_t, f);
  u += 0x7fff + ((u >> 16) & 1);
  return (unsigned short)(u >> 16);
}
__device__ __forceinline__ float bf2f(unsigned short h) {
  uint32_t u = ((uint32_t)h) << 16;
  return __builtin_bit_cast(float, u);
}
// pack two fp32 -> one u32 of 2 RNE bf16 (elem a in low half)
__device__ __forceinline__ uint32_t pk2(float a, float b) {
  return (uint32_t)f2bf_rne(a) | ((uint32_t)f2bf_rne(b) << 16);
}

// ---------------------------------------------------------------------------
// Gate: fp32 logits -> softmax -> top2 -> renorm weights; expert histogram.
// Fused: residual init (out = x).
__global__ __launch_bounds__(256) void k_gate(
    const float* __restrict__ x, const float* __restrict__ gw,
    float* __restrict__ outp, int4* __restrict__ tokexp, int* __restrict__ counts)
{
  __shared__ float gwT[8][1024];
  __shared__ int cnt[8];
  int tid = threadIdx.x;
  if (tid < 8) cnt[tid] = 0;
  for (int i = tid; i < D_IN * N_EXP; i += 256) gwT[i & 7][i >> 3] = gw[i];
  __syncthreads();
  int wave = tid >> 6, lane = tid & 63;
  for (int tt = 0; tt < 16; ++tt) {
    int t = blockIdx.x * 64 + wave * 16 + tt;
    const float4* x4 = (const float4*)(x + (size_t)t * D_IN);
    float4 v[4];
#pragma unroll
    for (int j = 0; j < 4; ++j) v[j] = x4[j * 64 + lane];
    // residual init
#pragma unroll
    for (int j = 0; j < 4; ++j) {
      size_t off = (size_t)t * D_IN + (size_t)(j * 64 + lane) * 4;
      *(float4*)(outp + off) = v[j];
    }
    float a[8];
#pragma unroll
    for (int e = 0; e < 8; ++e) a[e] = 0.f;
#pragma unroll
    for (int e = 0; e < 8; ++e) {
#pragma unroll
      for (int j = 0; j < 4; ++j) {
        float4 g4 = ((const float4*)gwT[e])[j * 64 + lane];
        float* vp = (float*)&v[j];
        a[e] += vp[0] * g4.x + vp[1] * g4.y + vp[2] * g4.z + vp[3] * g4.w;
      }
    }
#pragma unroll
    for (int e = 0; e < 8; ++e) {
#pragma unroll
      for (int s = 32; s >= 1; s >>= 1) a[e] += __shfl_xor(a[e], s, 64);
    }
    if (lane == 0) {
      float m = a[0];
#pragma unroll
      for (int e = 1; e < 8; ++e) m = fmaxf(m, a[e]);
      float g[8], s = 0.f;
#pragma unroll
      for (int e = 0; e < 8; ++e) { g[e] = expf(a[e] - m); s += g[e]; }
      float inv = 1.f / s;
#pragma unroll
      for (int e = 0; e < 8; ++e) g[e] *= inv;
      int i0 = 0; float v0 = g[0];
#pragma unroll
      for (int e = 1; e < 8; ++e) if (g[e] > v0) { v0 = g[e]; i0 = e; }
      int i1 = -1; float v1 = -1.f;
#pragma unroll
      for (int e = 0; e < 8; ++e) if (e != i0 && g[e] > v1) { v1 = g[e]; i1 = e; }
      float d = v0 + v1 + 1e-8f;
      int4 te; te.x = i0; te.y = i1;
      te.z = __float_as_int(v0 / d); te.w = __float_as_int(v1 / d);
      tokexp[t] = te;
      atomicAdd(&cnt[i0], 1); atomicAdd(&cnt[i1], 1);
    }
  }
  __syncthreads();
  if (tid < 8) atomicAdd(&counts[tid], cnt[tid]);
}

// ---------------------------------------------------------------------------
// Padded prefix offsets + rowblock->expert map (parallel mapxp fill).
__global__ void k_offsets(const int* __restrict__ counts, int* __restrict__ offs,
                          int* __restrict__ rbStart, int* __restrict__ mapxp,
                          int* __restrict__ cursors)
{
  __shared__ int s_rb[9], s_off[9];
  int tid = threadIdx.x;
  if (tid == 0) {
    int off = 0, rb = 0;
    for (int e = 0; e < 8; ++e) {
      s_off[e] = off; s_rb[e] = rb;
      int nrb = (counts[e] + 127) >> 7;
      off += nrb * 128; rb += nrb;
    }
    s_off[8] = off; s_rb[8] = rb;
  }
  __syncthreads();
  if (tid < 9) { offs[tid] = s_off[tid]; rbStart[tid] = s_rb[tid]; }
  if (tid < 8) cursors[tid] = 0;
  for (int i = tid; i < 1024; i += 64) {
    int v = -1;
#pragma unroll
    for (int e = 0; e < 8; ++e) if (i >= s_rb[e] && i < s_rb[e + 1]) v = e;
    mapxp[i] = v;
  }
}

// ---------------------------------------------------------------------------
// Assign each (token, slot) a compact row.
__global__ __launch_bounds__(256) void k_assign(
    const int4* __restrict__ tokexp, const int* __restrict__ offs,
    int* __restrict__ cursors, int* __restrict__ rowtab, float* __restrict__ roww)
{
  __shared__ int cnt[8], base[8];
  int tid = threadIdx.x;
  if (tid < 8) cnt[tid] = 0;
  __syncthreads();
  int t = blockIdx.x * 256 + tid;
  int4 te = tokexp[t];
  int ex0 = te.x, ex1 = te.y;
  int lr0 = atomicAdd(&cnt[ex0], 1);
  int lr1 = atomicAdd(&cnt[ex1], 1);
  __syncthreads();
  if (tid < 8) base[tid] = atomicAdd(&cursors[tid], cnt[tid]);
  __syncthreads();
  int row0 = offs[ex0] + base[ex0] + lr0;
  int row1 = offs[ex1] + base[ex1] + lr1;
  rowtab[row0] = t; roww[row0] = __int_as_float(te.z);
  rowtab[row1] = t; roww[row1] = __int_as_float(te.w);
}

// ---------------------------------------------------------------------------
// Transpose [K][N] fp32 -> [N][K] bf16 hi/lo planes (blockIdx.z = local expert).
__global__ __launch_bounds__(256) void k_tsplit(
    const float* __restrict__ in, unsigned short* __restrict__ oh,
    unsigned short* __restrict__ ol, int K, int N)
{
  __shared__ float lds[64][65];
  int e = blockIdx.z;
  int n0 = blockIdx.x * 64, k0 = blockIdx.y * 64;
  const float* ine = in + (size_t)e * K * N;
  unsigned short* ohe = oh + (size_t)e * N * K;
  unsigned short* ole = ol + (size_t)e * N * K;
  int tid = threadIdx.x;
#pragma unroll
  for (int i = 0; i < 8; ++i) {
    int idx = tid + i * 256;
    int r = idx >> 5, c2 = (idx & 31) * 2;
    float2 f = *(const float2*)(ine + (size_t)(k0 + r) * N + n0 + c2);
    lds[r][c2] = f.x; lds[r][c2 + 1] = f.y;
  }
  __syncthreads();
#pragma unroll
  for (int i = 0; i < 8; ++i) {
    int idx = tid + i * 256;
    int r = idx >> 5, c2 = (idx & 31) * 2;
    float a = lds[c2][r], b = lds[c2 + 1][r];
    ushort2 h2, l2;
    h2.x = f2bf_rne(a); l2.x = f2bf_rne(a - bf2f(h2.x));
    h2.y = f2bf_rne(b); l2.y = f2bf_rne(b - bf2f(h2.y));
    size_t o = (size_t)(n0 + r) * K + k0 + c2;
    *(ushort2*)(ohe + o) = h2;
    *(ushort2*)(ole + o) = l2;
  }
}

// ---------------------------------------------------------------------------
// bf16x2 GEMM, 128x128 tile, BK=64, 4 waves (2x2 of 64x64), 16x16x32 MFMA.
// Terms: ah*bh + ah*bl  (A RNE-rounded to bf16; B split hi/lo).
// G1: A = x fp32 (gathered rows, reg-staged RNE-bf16). epi: relu -> h (RNE).
// G2: A = h bf16 (global_load_lds; A is exact bf16).   epi: *w -> atomicAdd.
// LDS granule-XOR swizzle: LDS[row][g] = src[row][g ^ (row&7)], granule=16B.
// PROVEN r2/r5/r6 sync structure (~1000 TF, MfmaUtil 44%, 0 bank conflicts).
// Do not edit the sync structure without a race-screened A/B.
template <bool G1>
__global__ __launch_bounds__(256, 3) void k_gemm(
    const float* __restrict__ xA, const unsigned short* __restrict__ hA,
    const unsigned short* __restrict__ Bh, const unsigned short* __restrict__ Bl,
    const int* __restrict__ rbStart, const int* __restrict__ mapxp,
    const int* __restrict__ rowtab, const float* __restrict__ bias,
    const float* __restrict__ roww,
    unsigned short* __restrict__ Hh, float* __restrict__ outp,
    int g, int epg, int sc, int ch_rb)
{
  constexpr int K  = G1 ? D_IN : D_HID;
  constexpr int NT = G1 ? D_HID : D_OUT;
  constexpr int NB = G1 ? (D_HID / 128) : (D_OUT / 128);

  // bijective XCD swizzle (grid is a multiple of 8)
  int nwg = gridDim.x, orig = blockIdx.x;
  int wgid = (orig & 7) * (nwg >> 3) + (orig >> 3);
  int nb = wgid % NB;
  int by = wgid / NB;

  int gbase = rbStart[g * epg], gend = rbStart[g * epg + epg];
  int rb = gbase + sc * ch_rb + by;
  if (rb >= gend) return;
  int e = mapxp[rb];
  if (e < 0) return;
  int eL = e - g * epg;

  __shared__ unsigned short sAh[128 * 64];
  __shared__ unsigned short sBh[128 * 64], sBl[128 * 64];
  __shared__ float sbias[128], sw[128];
  __shared__ int srowt[128];

  int tid = threadIdx.x, lane = tid & 63, wave = tid >> 6;
  int wm = wave >> 1, wn = wave & 1;
  if (tid < 128) {
    sbias[tid] = bias[(size_t)e * NT + nb * 128 + tid];
    if constexpr (!G1) {
      sw[tid] = roww[rb * 128 + tid];
      srowt[tid] = rowtab[rb * 128 + tid];
    }
  }

  int sgu = ((tid & 7) ^ ((tid >> 3) & 7)) * 8;  // pre-swizzled source granule
  size_t bbase[4];
#pragma unroll
  for (int i = 0; i < 4; ++i)
    bbase[i] = ((size_t)eL * NT + nb * 128 + i * 32 + (tid >> 3)) * K + sgu;

  size_t abase[4]; size_t srcb[2]; int arow[2], ag0[2];
  if constexpr (G1) {
    int cc = tid & 3;
#pragma unroll
    for (int it = 0; it < 2; ++it) {
      int rr = it * 64 + (tid >> 2);
      arow[it] = rr;
      ag0[it] = ((2 * cc) ^ (rr & 7)) * 8;
      int t = rowtab[rb * 128 + rr];
      srcb[it] = (size_t)t * D_IN + cc * 16;
    }
  } else {
#pragma unroll
    for (int i = 0; i < 4; ++i)
      abase[i] = ((size_t)by * 128 + i * 32 + (tid >> 3)) * D_HID + sgu;
  }

  f32x4 acc[4][4];
#pragma unroll
  for (int mi = 0; mi < 4; ++mi)
#pragma unroll
    for (int nj = 0; nj < 4; ++nj) acc[mi][nj] = (f32x4){0.f, 0.f, 0.f, 0.f};

  for (int kk = 0; kk < K; kk += 64) {
#pragma unroll
    for (int i = 0; i < 4; ++i) {
      int d = i * 2048 + wave * 512;
      __builtin_amdgcn_global_load_lds((const GLB_AS void*)(Bh + bbase[i] + kk),
                                       (LDS_AS void*)(&sBh[d]), 16, 0, 0);
      __builtin_amdgcn_global_load_lds((const GLB_AS void*)(Bl + bbase[i] + kk),
                                       (LDS_AS void*)(&sBl[d]), 16, 0, 0);
      if constexpr (!G1) {
        __builtin_amdgcn_global_load_lds((const GLB_AS void*)(hA + abase[i] + kk),
                                         (LDS_AS void*)(&sAh[d]), 16, 0, 0);
      }
    }
    if constexpr (G1) {
#pragma unroll
      for (int it = 0; it < 2; ++it) {
        const float4* s = (const float4*)(xA + srcb[it] + kk);
        float4 f0 = s[0], f1 = s[1], f2 = s[2], f3 = s[3];
        uint4 H0, H1;
        H0.x = pk2(f0.x, f0.y); H0.y = pk2(f0.z, f0.w);
        H0.z = pk2(f1.x, f1.y); H0.w = pk2(f1.z, f1.w);
        H1.x = pk2(f2.x, f2.y); H1.y = pk2(f2.z, f2.w);
        H1.z = pk2(f3.x, f3.y); H1.w = pk2(f3.z, f3.w);
        int wo = arow[it] * 64;
        *(uint4*)&sAh[wo + ag0[it]]       = H0;
        *(uint4*)&sAh[wo + (ag0[it] ^ 8)] = H1;
      }
    }
    asm volatile("s_waitcnt vmcnt(0)" ::: "memory");
    __syncthreads();
#pragma unroll
    for (int kh = 0; kh < 2; ++kh) {
      int co = ((kh * 4 + (lane >> 4)) ^ (lane & 7)) * 8;
      short8 a_h[4];
#pragma unroll
      for (int mi = 0; mi < 4; ++mi) {
        int row = wm * 64 + mi * 16 + (lane & 15);
        a_h[mi] = *(const short8*)&sAh[row * 64 + co];
      }
#pragma unroll
      for (int nj = 0; nj < 4; ++nj) {
        int rowb = wn * 64 + nj * 16 + (lane & 15);
        short8 b_h = *(const short8*)&sBh[rowb * 64 + co];
        short8 b_l = *(const short8*)&sBl[rowb * 64 + co];
#pragma unroll
        for (int mi = 0; mi < 4; ++mi) {
          acc[mi][nj] = __builtin_amdgcn_mfma_f32_16x16x32_bf16(a_h[mi], b_h, acc[mi][nj], 0, 0, 0);
          acc[mi][nj] = __builtin_amdgcn_mfma_f32_16x16x32_bf16(a_h[mi], b_l, acc[mi][nj], 0, 0, 0);
        }
      }
    }
    __syncthreads();
  }
  // epilogue; C/D layout: col = lane&15, row = (lane>>4)*4 + r
#pragma unroll
  for (int mi = 0; mi < 4; ++mi)
#pragma unroll
    for (int nj = 0; nj < 4; ++nj) {
      int colL = wn * 64 + nj * 16 + (lane & 15);
#pragma unroll
      for (int r = 0; r < 4; ++r) {
        int rowL = wm * 64 + mi * 16 + (lane >> 4) * 4 + r;
        float v = acc[mi][nj][r] + sbias[colL];
        if constexpr (G1) {
          v = fmaxf(v, 0.f);
          size_t o = ((size_t)by * 128 + rowL) * D_HID + nb * 128 + colL;
          Hh[o] = f2bf_rne(v);
        } else {
          float w = sw[rowL];
          if (w != 0.f)
            atomicAdd(outp + (size_t)srowt[rowL] * D_OUT + nb * 128 + colL, v * w);
        }
      }
    }
}

// ---------------------------------------------------------------------------
extern "C" void kernel_launch(void* const* d_in, const int* in_sizes, int n_in,
                              void* d_out, int out_size, void* d_ws, size_t ws_size,
                              hipStream_t stream)
{
  const float* x  = (const float*)d_in[0];
  const float* gw = (const float*)d_in[1];
  const float* W1 = (const float*)d_in[2];
  const float* b1 = (const float*)d_in[3];
  const float* W2 = (const float*)d_in[4];
  const float* b2 = (const float*)d_in[5];
  float* out = (float*)d_out;
  (void)in_sizes; (void)n_in; (void)out_size;

  char* ws = (char*)d_ws;
  size_t o = 0;
  auto alloc = [&](size_t b) -> void* {
    void* p = ws + o; o += (b + 1023) & ~(size_t)1023; return p;
  };
  int*   counts  = (int*)alloc(1024);
  int*   cursors = (int*)alloc(1024);
  int*   offs    = (int*)alloc(1024);
  int*   rbStart = (int*)alloc(1024);
  int*   mapxp   = (int*)alloc(4096);
  int*   rowtab  = (int*)alloc(MAX_ROWS * 4);
  float* roww    = (float*)alloc(MAX_ROWS * 4);
  size_t zero_end = o;
  int4*  tokexp  = (int4*)alloc((size_t)T_TOKENS * 16);
  size_t small_end = o;

  // adaptive sizing: EPG experts per weight-group, CH row-blocks per h-chunk
  const size_t PER_EXP_W = ((size_t)D_IN * D_HID + (size_t)D_HID * D_OUT) * 2 * 2; // hi+lo bytes
  const size_t PER_RB_H  = (size_t)128 * D_HID * 2;                                // hi-only bytes
  int EPG = 1, CH = 1;
  {
    int bestE = 0, bestC = 0;
    const int cands[4] = {8, 4, 2, 1};
    for (int ci = 0; ci < 4; ++ci) {
      int cand = cands[ci];
      size_t fixed = small_end + (size_t)cand * PER_EXP_W + (1u << 20);
      if (ws_size <= fixed + PER_RB_H) continue;
      size_t hav = ws_size - fixed;
      int wmax = (cand * 128 < 256 + cand) ? cand * 128 : 256 + cand;
      int ch = (int)(hav / PER_RB_H);
      if (ch > wmax) ch = wmax;
      int goal = wmax < 33 ? wmax : 33;
      if (ch >= goal) { bestE = cand; bestC = ch; break; }
      if (ch > bestC) { bestE = cand; bestC = ch; }
    }
    if (bestE > 0) { EPG = bestE; CH = bestC; }
  }
  const int NGRP = 8 / EPG;
  const int WMAX = (EPG * 128 < 256 + EPG) ? EPG * 128 : 256 + EPG;
  const int NSC  = (WMAX + CH - 1) / CH;

  unsigned short* w1th = (unsigned short*)alloc((size_t)EPG * D_IN * D_HID * 2);
  unsigned short* w1tl = (unsigned short*)alloc((size_t)EPG * D_IN * D_HID * 2);
  unsigned short* w2th = (unsigned short*)alloc((size_t)EPG * D_HID * D_OUT * 2);
  unsigned short* w2tl = (unsigned short*)alloc((size_t)EPG * D_HID * D_OUT * 2);
  unsigned short* hh   = (unsigned short*)alloc((size_t)CH * 128 * D_HID * 2);

  hipMemsetAsync(ws, 0, zero_end, stream);
  k_gate<<<T_TOKENS / 64, 256, 0, stream>>>(x, gw, out, tokexp, counts);
  k_offsets<<<1, 64, 0, stream>>>(counts, offs, rbStart, mapxp, cursors);
  k_assign<<<T_TOKENS / 256, 256, 0, stream>>>(tokexp, offs, cursors, rowtab, roww);

  for (int g = 0; g < NGRP; ++g) {
    k_tsplit<<<dim3(D_HID / 64, D_IN / 64, EPG), 256, 0, stream>>>(
        W1 + (size_t)g * EPG * D_IN * D_HID, w1th, w1tl, D_IN, D_HID);
    k_tsplit<<<dim3(D_OUT / 64, D_HID / 64, EPG), 256, 0, stream>>>(
        W2 + (size_t)g * EPG * D_HID * D_OUT, w2th, w2tl, D_HID, D_OUT);
    for (int sc = 0; sc < NSC; ++sc) {
      k_gemm<true><<<dim3(16 * CH), 256, 0, stream>>>(
          x, nullptr, w1th, w1tl, rbStart, mapxp, rowtab, b1, roww,
          hh, nullptr, g, EPG, sc, CH);
      k_gemm<false><<<dim3(8 * CH), 256, 0, stream>>>(
          nullptr, hh, w2th, w2tl, rbStart, mapxp, rowtab, b2, roww,
          nullptr, out, g, EPG, sc, CH);
    }
  }
}